// Round 3
// baseline (187.568 us; speedup 1.0000x reference)
//
#include <hip/hip_runtime.h>

// CRF NLL on MI355X — round 13: single fused kernel.
// (1) Emissions burst-loaded per block: 64x64 feats chunk -> exp2 -> LDS
//     (coalesced float4, full MLP) — removes the per-cstep dependent global
//     load that capped chunks at 200 GB/s effective.
// (2) combine fused as a per-chain tail: after Pg/Eg stores, device-scope
//     fence + atomicAdd on a per-chain counter; 8th arriving block runs the
//     r12-verified matrix merge tree + final contraction + gold for its
//     chain. No second dispatch; per-chain combines overlap other chains'
//     chunk work. Counters/out zeroed via hipMemsetAsync (graph-capturable).

#define SS 512
#define TT 64
#define CC 8
#define KCH 64
#define START_TAG 62
#define END_TAG 63
#define LOG2E_F 1.44269504088896340736f
#define LN2_F 0.69314718055994530942f

#define WS_ECOL_OFF 4194304
#define WS_CNT_OFF  4325376
#define MSTR 72   // merge-LDS row stride in halfs (16B-aligned rows, bank-spread)

typedef float v4f __attribute__((ext_vector_type(4)));
typedef _Float16 h4 __attribute__((ext_vector_type(4)));
typedef __fp16 c2 __attribute__((ext_vector_type(2)));
union H4u { h4 v; struct { c2 lo, hi; } p; };

// ---------------- per-step core (LDS-emission variant of r9 cstep) ----------------
__device__ __forceinline__ void estep(const h4 (&A)[4][4], h4 (&B)[4],
                                      const float* __restrict__ emrow,
                                      int q, int& esum, int& esc) {
    v4f z = {0.f, 0.f, 0.f, 0.f};
    v4f D[4];
#pragma unroll
    for (int mt = 0; mt < 4; ++mt) {
        v4f a = __builtin_amdgcn_mfma_f32_16x16x16f16(A[mt][0], B[0], z, 0, 0, 0);
        a = __builtin_amdgcn_mfma_f32_16x16x16f16(A[mt][1], B[1], a, 0, 0, 0);
        v4f b = __builtin_amdgcn_mfma_f32_16x16x16f16(A[mt][2], B[2], z, 0, 0, 0);
        b = __builtin_amdgcn_mfma_f32_16x16x16f16(A[mt][3], B[3], b, 0, 0, 0);
        D[mt] = a + b;
    }
    esum += esc;
    float scf = __uint_as_float((unsigned)(127 - esc) << 23);
    v4f qs[4];
#pragma unroll
    for (int mt = 0; mt < 4; ++mt) {
        v4f em = *(const v4f*)(emrow + 16 * mt + 4 * q);
        qs[mt] = D[mt] * (em * scf);
    }
#pragma unroll
    for (int mt = 0; mt < 4; ++mt) {
        H4u u;
        u.p.lo = __builtin_amdgcn_cvt_pkrtz(qs[mt].x, qs[mt].y);
        u.p.hi = __builtin_amdgcn_cvt_pkrtz(qs[mt].z, qs[mt].w);
        B[mt] = u.v;
    }
    unsigned u0 = (unsigned)__builtin_amdgcn_readfirstlane((int)__float_as_uint(qs[0].x));
    esc = (int)((u0 >> 23) & 255u) - 127;
}

// ---------------- combine helpers (r12-verified) ----------------
__device__ __forceinline__ int wimax64(int v) {
#pragma unroll
    for (int m = 1; m < 64; m <<= 1) v = max(v, __shfl_xor(v, m, 64));
    return v;
}
__device__ __forceinline__ float wfmax64(float v) {
#pragma unroll
    for (int m = 1; m < 64; m <<= 1) v = fmaxf(v, __shfl_xor(v, m, 64));
    return v;
}
__device__ __forceinline__ float wfsum64(float v) {
#pragma unroll
    for (int m = 1; m < 64; m <<= 1) v += __shfl_xor(v, m, 64);
    return v;
}
__device__ __forceinline__ int fexp(float m) {
    unsigned u = (unsigned)__builtin_amdgcn_readfirstlane((int)__float_as_uint(m));
    return u ? (int)((u >> 23) & 255u) - 127 : 0;
}
__device__ __forceinline__ void mm64(const h4 (&A)[4][4], const h4 (&B)[4], v4f (&D)[4]) {
    v4f z = {0.f, 0.f, 0.f, 0.f};
#pragma unroll
    for (int mt = 0; mt < 4; ++mt) {
        v4f a = __builtin_amdgcn_mfma_f32_16x16x16f16(A[mt][0], B[0], z, 0, 0, 0);
        a = __builtin_amdgcn_mfma_f32_16x16x16f16(A[mt][1], B[1], a, 0, 0, 0);
        v4f b = __builtin_amdgcn_mfma_f32_16x16x16f16(A[mt][2], B[2], z, 0, 0, 0);
        b = __builtin_amdgcn_mfma_f32_16x16x16f16(A[mt][3], B[3], b, 0, 0, 0);
        D[mt] = a + b;
    }
}
__device__ __forceinline__ float dmax16(const v4f (&D)[4]) {
    float m = 0.f;
#pragma unroll
    for (int mt = 0; mt < 4; ++mt)
        m = fmaxf(m, fmaxf(fmaxf(D[mt].x, D[mt].y), fmaxf(D[mt].z, D[mt].w)));
    return m;
}
__device__ __forceinline__ void prodG(const unsigned short* __restrict__ PgC, int cA, int cB,
                                      const float* __restrict__ sAt,
                                      int n16, int q, int ncol, v4f (&D)[4]) {
    const _Float16* Ap = (const _Float16*)PgC + cA * 4096;
    const _Float16* Bp = (const _Float16*)PgC + cB * 4096;
    h4 Af[4][4];
#pragma unroll
    for (int mt = 0; mt < 4; ++mt)
#pragma unroll
        for (int ks = 0; ks < 4; ++ks) {
            h4 raw = *(const h4*)(Ap + (16 * mt + n16) * TT + 16 * ks + 4 * q);
            v4f s = *(const v4f*)(sAt + 16 * ks + 4 * q);
            h4 a;
#pragma unroll
            for (int e = 0; e < 4; ++e) a[e] = (_Float16)((float)raw[e] * s[e]);
            Af[mt][ks] = a;
        }
    h4 Bf[4];
#pragma unroll
    for (int ks = 0; ks < 4; ++ks) {
        h4 b;
#pragma unroll
        for (int j = 0; j < 4; ++j) b[j] = Bp[(16 * ks + 4 * q + j) * TT + ncol];
        Bf[ks] = b;
    }
    mm64(Af, Bf, D);
}

// ---------------- fused kernel ----------------
__global__ __launch_bounds__(256, 1)
void crf_fused(const float* __restrict__ feats, const float* __restrict__ trans,
               const int* __restrict__ mask, const int* __restrict__ tags,
               unsigned short* __restrict__ Pg, int* __restrict__ Eg,
               unsigned* __restrict__ cnt, float* __restrict__ out) {
    __shared__ __align__(16) float emS[KCH][TT];          // 16 KB emissions
    __shared__ __align__(16) _Float16 mldB[TT * MSTR];    // 9.2 KB (tail reuses as stg)
    __shared__ __align__(16) _Float16 mldD[TT * MSTR];    // 9.2 KB
    __shared__ int ebuf[12];
    __shared__ int lastf;
    __shared__ __align__(16) float sA[4][TT];
    __shared__ __align__(16) float wend[TT];
    __shared__ int eodd[4];
    __shared__ int ib0[4], ib1[4], ib2[4], ib3[4];
    __shared__ float redf[4], gred[4];

    const int blk = blockIdx.x;
    const int chain = blk >> 3, c = blk & 7;
    const int tid = threadIdx.x;
    const int w = tid >> 6, l = tid & 63;
    const int n16 = l & 15, q = l >> 4;
    const int ncol = 16 * w + n16;

    // A = E^T stationary frags from trans
    h4 A[4][4];
#pragma unroll
    for (int mt = 0; mt < 4; ++mt)
#pragma unroll
        for (int ks = 0; ks < 4; ++ks) {
            h4 a;
#pragma unroll
            for (int e = 0; e < 4; ++e)
                a[e] = (_Float16)__builtin_amdgcn_exp2f(
                    trans[(16 * ks + 4 * q + e) * TT + 16 * mt + n16] * LOG2E_F);
            A[mt][ks] = a;
        }

    // chain length L
    const int* mp = mask + chain * SS;
    int msum = 0;
#pragma unroll
    for (int k = 0; k < 8; ++k) msum += mp[k * 64 + l];
#pragma unroll
    for (int s_ = 1; s_ < 64; s_ <<= 1) msum += __shfl_xor(msum, s_, 64);
    const int L = msum;

    const int t0a = 1 + KCH * c;
    const int base = (L - 1) - KCH * c;
    int nA = base < 0 ? 0 : (base > 16 ? 16 : base);
    int nB = base - 16 < 0 ? 0 : (base - 16 > 16 ? 16 : base - 16);
    int nC = base - 32 < 0 ? 0 : (base - 32 > 16 ? 16 : base - 32);
    int nD = base - 48 < 0 ? 0 : (base - 48 > 16 ? 16 : base - 48);

    // ---- burst-load emissions: 64 timesteps x 64 tags, exp2'd into LDS ----
    const float* fbase = feats + (size_t)chain * SS * TT;
#pragma unroll
    for (int k = 0; k < 4; ++k) {
        int idx = tid + 256 * k;      // 0..1023
        int row = idx >> 4;           // 0..63
        int seg = idx & 15;           // 16B segment
        int t = t0a + row;
        t = t < SS ? t : SS - 1;
        v4f v = *(const v4f*)(fbase + (size_t)t * TT + 4 * seg);
        v4f e;
        e.x = __builtin_amdgcn_exp2f(v.x * LOG2E_F);
        e.y = __builtin_amdgcn_exp2f(v.y * LOG2E_F);
        e.z = __builtin_amdgcn_exp2f(v.z * LOG2E_F);
        e.w = __builtin_amdgcn_exp2f(v.w * LOG2E_F);
        *(v4f*)(&emS[row][4 * seg]) = e;
    }

    // identity inits
    h4 Ba[4], Bb[4], Bc[4], Bd[4];
#pragma unroll
    for (int ks = 0; ks < 4; ++ks) {
        h4 b;
#pragma unroll
        for (int jj = 0; jj < 4; ++jj)
            b[jj] = (_Float16)((16 * ks + 4 * q + jj == ncol) ? 1.f : 0.f);
        Ba[ks] = b; Bb[ks] = b; Bc[ks] = b; Bd[ks] = b;
    }
    __syncthreads();  // emS ready

    int esA = 0, escA = 0, esB = 0, escB = 0;
    int esC = 0, escC = 0, esD = 0, escD = 0;

    if (nD == 16) {  // all four sub-chains full: branch-free hot path
        for (int r = 0; r < 8; ++r) {
            const int s0 = 2 * r;
            estep(A, Ba, &emS[s0][0],      q, esA, escA);
            estep(A, Bb, &emS[16 + s0][0], q, esB, escB);
            estep(A, Bc, &emS[32 + s0][0], q, esC, escC);
            estep(A, Bd, &emS[48 + s0][0], q, esD, escD);
            estep(A, Ba, &emS[s0 + 1][0],      q, esA, escA);
            estep(A, Bb, &emS[17 + s0][0], q, esB, escB);
            estep(A, Bc, &emS[33 + s0][0], q, esC, escC);
            estep(A, Bd, &emS[49 + s0][0], q, esD, escD);
        }
    } else {  // boundary chunk: uniform-predicated
        for (int r = 0; r < 8; ++r) {
            const int s0 = 2 * r, s1 = s0 + 1;
            if (s0 < nA) estep(A, Ba, &emS[s0][0],      q, esA, escA);
            if (s0 < nB) estep(A, Bb, &emS[16 + s0][0], q, esB, escB);
            if (s0 < nC) estep(A, Bc, &emS[32 + s0][0], q, esC, escC);
            if (s0 < nD) estep(A, Bd, &emS[48 + s0][0], q, esD, escD);
            if (s1 < nA) estep(A, Ba, &emS[s1][0],      q, esA, escA);
            if (s1 < nB) estep(A, Bb, &emS[16 + s1][0], q, esB, escB);
            if (s1 < nC) estep(A, Bc, &emS[32 + s1][0], q, esC, escC);
            if (s1 < nD) estep(A, Bd, &emS[48 + s1][0], q, esD, escD);
        }
    }

    // ---- merge level 1: P1 = Hb*Ha, P2 = Hd*Hc (parallel) ----
    if (l == 0) { ebuf[w] = esB; ebuf[4 + w] = esD; }
    __syncthreads();
    const int eBmax = max(max(ebuf[0], ebuf[1]), max(ebuf[2], ebuf[3]));
    const int eDmax = max(max(ebuf[4], ebuf[5]), max(ebuf[6], ebuf[7]));
    {
        _Float16 sB = (_Float16)ldexpf(1.f, esB - eBmax);
        _Float16 sD = (_Float16)ldexpf(1.f, esD - eDmax);
        h4 s4B = {sB, sB, sB, sB}, s4D = {sD, sD, sD, sD};
#pragma unroll
        for (int ks = 0; ks < 4; ++ks) {
            h4 vb = Bb[ks] * s4B;
            h4 vd = Bd[ks] * s4D;
#pragma unroll
            for (int jj = 0; jj < 4; ++jj) {
                mldB[(16 * ks + 4 * q + jj) * MSTR + ncol] = vb[jj];
                mldD[(16 * ks + 4 * q + jj) * MSTR + ncol] = vd[jj];
            }
        }
    }
    __syncthreads();
    h4 AHb[4][4], AHd[4][4];
#pragma unroll
    for (int mt = 0; mt < 4; ++mt)
#pragma unroll
        for (int ks = 0; ks < 4; ++ks) {
            AHb[mt][ks] = *(const h4*)(mldB + (16 * mt + n16) * MSTR + 16 * ks + 4 * q);
            AHd[mt][ks] = *(const h4*)(mldD + (16 * mt + n16) * MSTR + 16 * ks + 4 * q);
        }
    v4f z = {0.f, 0.f, 0.f, 0.f};
    v4f P1[4], P2[4];
#pragma unroll
    for (int mt = 0; mt < 4; ++mt) {
        v4f a = __builtin_amdgcn_mfma_f32_16x16x16f16(AHb[mt][0], Ba[0], z, 0, 0, 0);
        a = __builtin_amdgcn_mfma_f32_16x16x16f16(AHb[mt][1], Ba[1], a, 0, 0, 0);
        v4f b = __builtin_amdgcn_mfma_f32_16x16x16f16(AHb[mt][2], Ba[2], z, 0, 0, 0);
        b = __builtin_amdgcn_mfma_f32_16x16x16f16(AHb[mt][3], Ba[3], b, 0, 0, 0);
        P1[mt] = a + b;
        v4f a2 = __builtin_amdgcn_mfma_f32_16x16x16f16(AHd[mt][0], Bc[0], z, 0, 0, 0);
        a2 = __builtin_amdgcn_mfma_f32_16x16x16f16(AHd[mt][1], Bc[1], a2, 0, 0, 0);
        v4f b2 = __builtin_amdgcn_mfma_f32_16x16x16f16(AHd[mt][2], Bc[2], z, 0, 0, 0);
        b2 = __builtin_amdgcn_mfma_f32_16x16x16f16(AHd[mt][3], Bc[3], b2, 0, 0, 0);
        P2[mt] = a2 + b2;
    }
    float m1 = 0.f, m2 = 0.f;
#pragma unroll
    for (int mt = 0; mt < 4; ++mt) {
        m1 = fmaxf(m1, fmaxf(fmaxf(P1[mt].x, P1[mt].y), fmaxf(P1[mt].z, P1[mt].w)));
        m2 = fmaxf(m2, fmaxf(fmaxf(P2[mt].x, P2[mt].y), fmaxf(P2[mt].z, P2[mt].w)));
    }
#pragma unroll
    for (int m = 1; m < 64; m <<= 1) {
        m1 = fmaxf(m1, __shfl_xor(m1, m, 64));
        m2 = fmaxf(m2, __shfl_xor(m2, m, 64));
    }
    unsigned u1 = (unsigned)__builtin_amdgcn_readfirstlane((int)__float_as_uint(m1));
    unsigned u2 = (unsigned)__builtin_amdgcn_readfirstlane((int)__float_as_uint(m2));
    const int e1c = u1 ? (int)((u1 >> 23) & 255u) - 127 : 0;
    const int e2c = u2 ? (int)((u2 >> 23) & 255u) - 127 : 0;
    const int e1 = esA + eBmax + e1c;
    const int e2 = esC + eDmax + e2c;
    h4 P1h[4], P2h[4];
    {
        float s1f = __uint_as_float((unsigned)(127 - e1c) << 23);
        float s2f = __uint_as_float((unsigned)(127 - e2c) << 23);
#pragma unroll
        for (int mt = 0; mt < 4; ++mt) {
            v4f q1 = P1[mt] * s1f;
            v4f q2 = P2[mt] * s2f;
            H4u ua, ub;
            ua.p.lo = __builtin_amdgcn_cvt_pkrtz(q1.x, q1.y);
            ua.p.hi = __builtin_amdgcn_cvt_pkrtz(q1.z, q1.w);
            ub.p.lo = __builtin_amdgcn_cvt_pkrtz(q2.x, q2.y);
            ub.p.hi = __builtin_amdgcn_cvt_pkrtz(q2.z, q2.w);
            P1h[mt] = ua.v;
            P2h[mt] = ub.v;
        }
    }

    // ---- merge level 2: R = P2 * P1 ----
    if (l == 0) ebuf[8 + w] = e2;
    __syncthreads();
    const int e2max = max(max(ebuf[8], ebuf[9]), max(ebuf[10], ebuf[11]));
    {
        _Float16 s2 = (_Float16)ldexpf(1.f, e2 - e2max);
        h4 s4 = {s2, s2, s2, s2};
#pragma unroll
        for (int mt = 0; mt < 4; ++mt) {
            h4 v = P2h[mt] * s4;
#pragma unroll
            for (int jj = 0; jj < 4; ++jj)
                mldB[(16 * mt + 4 * q + jj) * MSTR + ncol] = v[jj];
        }
    }
    __syncthreads();
    h4 AHp[4][4];
#pragma unroll
    for (int mt = 0; mt < 4; ++mt)
#pragma unroll
        for (int ks = 0; ks < 4; ++ks)
            AHp[mt][ks] = *(const h4*)(mldB + (16 * mt + n16) * MSTR + 16 * ks + 4 * q);
    h4 Rf[4];
#pragma unroll
    for (int mt = 0; mt < 4; ++mt) {
        v4f a = __builtin_amdgcn_mfma_f32_16x16x16f16(AHp[mt][0], P1h[0], z, 0, 0, 0);
        a = __builtin_amdgcn_mfma_f32_16x16x16f16(AHp[mt][1], P1h[1], a, 0, 0, 0);
        v4f b = __builtin_amdgcn_mfma_f32_16x16x16f16(AHp[mt][2], P1h[2], z, 0, 0, 0);
        b = __builtin_amdgcn_mfma_f32_16x16x16f16(AHp[mt][3], P1h[3], b, 0, 0, 0);
        v4f d = a + b;
        H4u u;
        u.p.lo = __builtin_amdgcn_cvt_pkrtz(d.x, d.y);
        u.p.hi = __builtin_amdgcn_cvt_pkrtz(d.z, d.w);
        Rf[mt] = u.v;
    }
    __syncthreads();  // mldD reads (AHd) long done; reuse for output staging
#pragma unroll
    for (int mt = 0; mt < 4; ++mt)
#pragma unroll
        for (int jj = 0; jj < 4; ++jj)
            mldD[(16 * mt + 4 * q + jj) * MSTR + ncol] = Rf[mt][jj];
    __syncthreads();
    {
        const size_t base_ = ((size_t)chain * CC + c) * 4096;
        int r = tid >> 2, cb = tid & 3;
        const uint4* src = (const uint4*)(mldD + r * MSTR + cb * 16);
        uint4* dst = (uint4*)(Pg + base_ + r * TT + cb * 16);
        dst[0] = src[0];
        dst[1] = src[1];
    }
    if (q == 0) Eg[(chain * CC + c) * TT + ncol] = e1 + e2max;

    // ---- arrival protocol: 8th block of the chain runs the combine tail ----
    __syncthreads();      // drains vmcnt: all Pg/Eg stores of this block complete
    __threadfence();      // device-scope release (L2 writeback)
    if (tid == 0) {
        unsigned old = atomicAdd(&cnt[chain], 1u);
        lastf = (old == (unsigned)(CC - 1));
    }
    __syncthreads();
    if (!lastf) return;
    __threadfence();      // device-scope acquire (invalidate stale L1/L2)

    // ================= combine tail (r12-verified math) =================
    const unsigned short* PgC = Pg + (size_t)chain * CC * 4096;
    const int* EgC = Eg + chain * CC * TT;

    // gold partial: 2 positions per thread
    float g = 0.f;
#pragma unroll
    for (int rep = 0; rep < 2; ++rep) {
        int t = tid + rep * 256;
        if (t < L) {
            int cur = tags[chain * SS + t];
            int prev = t ? tags[chain * SS + t - 1] : START_TAG;
            g += fbase[(size_t)t * TT + cur] + trans[prev * TT + cur];
        }
    }
    g = wfsum64(g);
    if (l == 0) gred[w] = g;

    // fold tables for odd chunks
    {
        int e1t = EgC[(2 * w + 1) * TT + l];
        int em = wimax64(e1t);
        if (l == 0) eodd[w] = em;
        sA[w][l] = ldexpf(1.f, e1t - em);
    }
    if (tid < TT) wend[tid] = expf(trans[tid * TT + END_TAG]);
    __syncthreads();  // B1

    float pl = fbase[l] + trans[START_TAG * TT + l];
    float M0 = wfmax64(pl);
    float pc = fbase[ncol] + trans[START_TAG * TT + ncol];
    float p0c = __builtin_amdgcn_exp2f((pc - M0) * LOG2E_F);

    const int eqB0 = EgC[0 * TT + ncol];
    const int eqB1 = EgC[2 * TT + ncol];
    const int eqB2 = EgC[4 * TT + ncol];
    const int eqB3 = EgC[6 * TT + ncol];
    const int eo0 = eodd[0], eo1 = eodd[1], eo2 = eodd[2], eo3 = eodd[3];

    v4f D[4];
    // ---- Q1 = H3*H2 ----
    prodG(PgC, 3, 2, &sA[1][0], n16, q, ncol, D);
    int ec1 = fexp(wfmax64(dmax16(D)));
    int eq1 = eqB1 + eo1 + ec1;
    int eq1m = wimax64(eq1);
    if (l == 0) ib0[w] = eq1m;
    __syncthreads();  // B2
    const int emax1 = max(max(ib0[0], ib0[1]), max(ib0[2], ib0[3]));
    {
        float sc = ldexpf(1.f, eqB1 + eo1 - emax1);
#pragma unroll
        for (int mt = 0; mt < 4; ++mt)
#pragma unroll
            for (int jj = 0; jj < 4; ++jj)
                mldB[(16 * mt + 4 * q + jj) * MSTR + ncol] = (_Float16)(D[mt][jj] * sc);
    }
    // ---- Q0 = H1*H0 ----
    v4f D0[4];
    prodG(PgC, 1, 0, &sA[0][0], n16, q, ncol, D0);
    int ec0 = fexp(wfmax64(dmax16(D0)));
    int eq0 = eqB0 + eo0 + ec0;
    h4 Q0h[4];
    {
        float s0 = ldexpf(1.f, -ec0);
#pragma unroll
        for (int mt = 0; mt < 4; ++mt) {
            v4f qv = D0[mt] * s0;
            H4u u;
            u.p.lo = __builtin_amdgcn_cvt_pkrtz(qv.x, qv.y);
            u.p.hi = __builtin_amdgcn_cvt_pkrtz(qv.z, qv.w);
            Q0h[mt] = u.v;
        }
    }
    __syncthreads();  // B3: stg(Q1) ready
    h4 AH[4][4];
#pragma unroll
    for (int mt = 0; mt < 4; ++mt)
#pragma unroll
        for (int ks = 0; ks < 4; ++ks)
            AH[mt][ks] = *(const h4*)(mldB + (16 * mt + n16) * MSTR + 16 * ks + 4 * q);
    v4f Dlo[4];
    mm64(AH, Q0h, Dlo);
    int eclo = fexp(wfmax64(dmax16(Dlo)));
    int eqlo = eq0 + emax1 + eclo;
    h4 Ploh[4];
    {
        float sl = ldexpf(1.f, -eclo);
#pragma unroll
        for (int mt = 0; mt < 4; ++mt) {
            v4f qv = Dlo[mt] * sl;
            H4u u;
            u.p.lo = __builtin_amdgcn_cvt_pkrtz(qv.x, qv.y);
            u.p.hi = __builtin_amdgcn_cvt_pkrtz(qv.z, qv.w);
            Ploh[mt] = u.v;
        }
    }
    // ---- Q3 = H7*H6 ----
    prodG(PgC, 7, 6, &sA[3][0], n16, q, ncol, D);
    int ec3 = fexp(wfmax64(dmax16(D)));
    int eq3 = eqB3 + eo3 + ec3;
    int eq3m = wimax64(eq3);
    if (l == 0) ib1[w] = eq3m;
    __syncthreads();  // B4
    const int emax3 = max(max(ib1[0], ib1[1]), max(ib1[2], ib1[3]));
    {
        float sc = ldexpf(1.f, eqB3 + eo3 - emax3);
#pragma unroll
        for (int mt = 0; mt < 4; ++mt)
#pragma unroll
            for (int jj = 0; jj < 4; ++jj)
                mldB[(16 * mt + 4 * q + jj) * MSTR + ncol] = (_Float16)(D[mt][jj] * sc);
    }
    // ---- Q2 = H5*H4 ----
    v4f D2[4];
    prodG(PgC, 5, 4, &sA[2][0], n16, q, ncol, D2);
    int ec2 = fexp(wfmax64(dmax16(D2)));
    int eq2 = eqB2 + eo2 + ec2;
    h4 Q2h[4];
    {
        float s2 = ldexpf(1.f, -ec2);
#pragma unroll
        for (int mt = 0; mt < 4; ++mt) {
            v4f qv = D2[mt] * s2;
            H4u u;
            u.p.lo = __builtin_amdgcn_cvt_pkrtz(qv.x, qv.y);
            u.p.hi = __builtin_amdgcn_cvt_pkrtz(qv.z, qv.w);
            Q2h[mt] = u.v;
        }
    }
    __syncthreads();  // B5: stg(Q3) ready
#pragma unroll
    for (int mt = 0; mt < 4; ++mt)
#pragma unroll
        for (int ks = 0; ks < 4; ++ks)
            AH[mt][ks] = *(const h4*)(mldB + (16 * mt + n16) * MSTR + 16 * ks + 4 * q);
    v4f Dhi[4];
    mm64(AH, Q2h, Dhi);
    int echi = fexp(wfmax64(dmax16(Dhi)));
    int eqhi = eq2 + emax3 + echi;
    int eqhim = wimax64(eqhi);
    if (l == 0) ib2[w] = eqhim;
    __syncthreads();  // B6
    const int emaxhi = max(max(ib2[0], ib2[1]), max(ib2[2], ib2[3]));
    {
        float sc = ldexpf(1.f, eq2 + emax3 - emaxhi);
#pragma unroll
        for (int mt = 0; mt < 4; ++mt)
#pragma unroll
            for (int jj = 0; jj < 4; ++jj)
                mldB[(16 * mt + 4 * q + jj) * MSTR + ncol] = (_Float16)(Dhi[mt][jj] * sc);
    }
    __syncthreads();  // B7: stg(P_hi) ready
#pragma unroll
    for (int mt = 0; mt < 4; ++mt)
#pragma unroll
        for (int ks = 0; ks < 4; ++ks)
            AH[mt][ks] = *(const h4*)(mldB + (16 * mt + n16) * MSTR + 16 * ks + 4 * q);
    v4f DR[4];
    mm64(AH, Ploh, DR);

    // ---- final contraction: fwd = log( wend^T R p0 ) ----
    float zsum = 0.f;
#pragma unroll
    for (int mt = 0; mt < 4; ++mt) {
        v4f wv = *(const v4f*)(wend + 16 * mt + 4 * q);
        zsum += wv.x * DR[mt].x + wv.y * DR[mt].y + wv.z * DR[mt].z + wv.w * DR[mt].w;
    }
    zsum += __shfl_xor(zsum, 16, 64);
    zsum += __shfl_xor(zsum, 32, 64);
    float val = zsum * p0c;
    int ex = eqlo + emaxhi;
    int exm = wimax64(ex);
    float contrib = (q == 0) ? ldexpf(val, ex - exm) : 0.f;
    float Sw = wfsum64(contrib);
    if (l == 0) { redf[w] = Sw; ib3[w] = exm; }
    __syncthreads();  // B8
    if (tid == 0) {
        int gmax = max(max(ib3[0], ib3[1]), max(ib3[2], ib3[3]));
        float tot = 0.f;
#pragma unroll
        for (int p = 0; p < 4; ++p) tot += ldexpf(redf[p], ib3[p] - gmax);
        float fwd = logf(tot) + (float)gmax * LN2_F + M0;
        float gold = gred[0] + gred[1] + gred[2] + gred[3] +
                     trans[tags[chain * SS + L - 1] * TT + END_TAG];
        atomicAdd(out, fwd - gold);
    }
}

extern "C" void kernel_launch(void* const* d_in, const int* in_sizes, int n_in,
                              void* d_out, int out_size, void* d_ws, size_t ws_size,
                              hipStream_t stream) {
    const float* feats = (const float*)d_in[0];
    const float* trans = (const float*)d_in[1];
    const int*   mask  = (const int*)d_in[2];
    const int*   tags  = (const int*)d_in[3];
    float* out = (float*)d_out;
    unsigned short* Pg = (unsigned short*)d_ws;
    int*       Eg  = (int*)((char*)d_ws + WS_ECOL_OFF);
    unsigned*  cnt = (unsigned*)((char*)d_ws + WS_CNT_OFF);

    hipMemsetAsync((char*)d_ws + WS_CNT_OFF, 0, 64 * sizeof(unsigned), stream);
    hipMemsetAsync(d_out, 0, sizeof(float), stream);
    crf_fused<<<dim3(64 * CC), dim3(256), 0, stream>>>(feats, trans, mask, tags, Pg, Eg, cnt, out);
}

// Round 4
// 122.098 us; speedup vs baseline: 1.5362x; 1.5362x over previous
//
#include <hip/hip_runtime.h>

// CRF NLL on MI355X — round 14: two kernels, fence-free.
// K1 (chunks): r11 4-way-ILP chunk kernel, but emissions burst-loaded:
//   the 64x64 feats tile is read with coalesced float4 loads, exp2'd once
//   into LDS — removes the per-step dependent global load (200 GB/s MLP cap).
// K2 (combine): r12 matrix merge tree, verified absmax=0 twice. No fences,
//   no cross-block protocols (r13's per-block device fence cost ~+100 µs).

#define SS 512
#define TT 64
#define CC 8
#define KCH 64
#define START_TAG 62
#define END_TAG 63
#define LOG2E_F 1.44269504088896340736f
#define LN2_F 0.69314718055994530942f

#define WS_ECOL_OFF 4194304
#define MSTR 72   // merge-LDS row stride in halfs (16B-aligned rows, bank-spread)

typedef float v4f __attribute__((ext_vector_type(4)));
typedef _Float16 h4 __attribute__((ext_vector_type(4)));
typedef __fp16 c2 __attribute__((ext_vector_type(2)));
union H4u { h4 v; struct { c2 lo, hi; } p; };

// ---------------- per-step core: LDS-emission variant ----------------
__device__ __forceinline__ void estep(const h4 (&A)[4][4], h4 (&B)[4],
                                      const float* __restrict__ emrow,
                                      int q, int& esum, int& esc) {
    v4f z = {0.f, 0.f, 0.f, 0.f};
    v4f D[4];
#pragma unroll
    for (int mt = 0; mt < 4; ++mt) {
        v4f a = __builtin_amdgcn_mfma_f32_16x16x16f16(A[mt][0], B[0], z, 0, 0, 0);
        a = __builtin_amdgcn_mfma_f32_16x16x16f16(A[mt][1], B[1], a, 0, 0, 0);
        v4f b = __builtin_amdgcn_mfma_f32_16x16x16f16(A[mt][2], B[2], z, 0, 0, 0);
        b = __builtin_amdgcn_mfma_f32_16x16x16f16(A[mt][3], B[3], b, 0, 0, 0);
        D[mt] = a + b;
    }
    esum += esc;
    float scf = __uint_as_float((unsigned)(127 - esc) << 23);
    v4f qs[4];
#pragma unroll
    for (int mt = 0; mt < 4; ++mt) {
        v4f em = *(const v4f*)(emrow + 16 * mt + 4 * q);
        qs[mt] = D[mt] * (em * scf);
    }
#pragma unroll
    for (int mt = 0; mt < 4; ++mt) {
        H4u u;
        u.p.lo = __builtin_amdgcn_cvt_pkrtz(qs[mt].x, qs[mt].y);
        u.p.hi = __builtin_amdgcn_cvt_pkrtz(qs[mt].z, qs[mt].w);
        B[mt] = u.v;
    }
    unsigned u0 = (unsigned)__builtin_amdgcn_readfirstlane((int)__float_as_uint(qs[0].x));
    esc = (int)((u0 >> 23) & 255u) - 127;
}

// ---------------- chunk kernel: 4 sub-chains x 16 steps, LDS emissions ----------------
__global__ __launch_bounds__(256, 1)
void crf_chunks(const float* __restrict__ feats, const float* __restrict__ trans,
                const int* __restrict__ mask, unsigned short* __restrict__ Pg,
                int* __restrict__ Eg, float* __restrict__ out) {
    __shared__ __align__(16) float emS[KCH][TT];          // 16 KB emissions
    __shared__ __align__(16) _Float16 mldB[TT * MSTR];
    __shared__ __align__(16) _Float16 mldD[TT * MSTR];
    __shared__ int ebuf[12];

    const int blk = blockIdx.x;
    const int chain = blk >> 3, c = blk & 7;
    const int tid = threadIdx.x;
    const int w = tid >> 6, l = tid & 63;
    const int n16 = l & 15, q = l >> 4;
    const int ncol = 16 * w + n16;

    if (blk == 0 && tid == 0) out[0] = 0.f;

    // A = E^T stationary frags from trans
    h4 A[4][4];
#pragma unroll
    for (int mt = 0; mt < 4; ++mt)
#pragma unroll
        for (int ks = 0; ks < 4; ++ks) {
            h4 a;
#pragma unroll
            for (int e = 0; e < 4; ++e)
                a[e] = (_Float16)__builtin_amdgcn_exp2f(
                    trans[(16 * ks + 4 * q + e) * TT + 16 * mt + n16] * LOG2E_F);
            A[mt][ks] = a;
        }

    // chain length L
    const int* mp = mask + chain * SS;
    int msum = 0;
#pragma unroll
    for (int k = 0; k < 8; ++k) msum += mp[k * 64 + l];
#pragma unroll
    for (int s_ = 1; s_ < 64; s_ <<= 1) msum += __shfl_xor(msum, s_, 64);
    const int L = msum;

    const int t0a = 1 + KCH * c;
    const int base = (L - 1) - KCH * c;
    int nA = base < 0 ? 0 : (base > 16 ? 16 : base);
    int nB = base - 16 < 0 ? 0 : (base - 16 > 16 ? 16 : base - 16);
    int nC = base - 32 < 0 ? 0 : (base - 32 > 16 ? 16 : base - 32);
    int nD = base - 48 < 0 ? 0 : (base - 48 > 16 ? 16 : base - 48);

    // ---- burst-load emissions: 64 timesteps x 64 tags, exp2'd into LDS ----
    const float* fbase = feats + (size_t)chain * SS * TT;
#pragma unroll
    for (int k = 0; k < 4; ++k) {
        int idx = tid + 256 * k;      // 0..1023
        int row = idx >> 4;           // 0..63
        int seg = idx & 15;           // 16B segment
        int t = t0a + row;
        t = t < SS ? t : SS - 1;
        v4f v = *(const v4f*)(fbase + (size_t)t * TT + 4 * seg);
        v4f e;
        e.x = __builtin_amdgcn_exp2f(v.x * LOG2E_F);
        e.y = __builtin_amdgcn_exp2f(v.y * LOG2E_F);
        e.z = __builtin_amdgcn_exp2f(v.z * LOG2E_F);
        e.w = __builtin_amdgcn_exp2f(v.w * LOG2E_F);
        *(v4f*)(&emS[row][4 * seg]) = e;
    }

    // identity inits
    h4 Ba[4], Bb[4], Bc[4], Bd[4];
#pragma unroll
    for (int ks = 0; ks < 4; ++ks) {
        h4 b;
#pragma unroll
        for (int jj = 0; jj < 4; ++jj)
            b[jj] = (_Float16)((16 * ks + 4 * q + jj == ncol) ? 1.f : 0.f);
        Ba[ks] = b; Bb[ks] = b; Bc[ks] = b; Bd[ks] = b;
    }
    __syncthreads();  // emS ready

    int esA = 0, escA = 0, esB = 0, escB = 0;
    int esC = 0, escC = 0, esD = 0, escD = 0;

    if (nD == 16) {  // all four sub-chains full: branch-free hot path
        for (int r = 0; r < 8; ++r) {
            const int s0 = 2 * r;
            estep(A, Ba, &emS[s0][0],      q, esA, escA);
            estep(A, Bb, &emS[16 + s0][0], q, esB, escB);
            estep(A, Bc, &emS[32 + s0][0], q, esC, escC);
            estep(A, Bd, &emS[48 + s0][0], q, esD, escD);
            estep(A, Ba, &emS[s0 + 1][0],  q, esA, escA);
            estep(A, Bb, &emS[17 + s0][0], q, esB, escB);
            estep(A, Bc, &emS[33 + s0][0], q, esC, escC);
            estep(A, Bd, &emS[49 + s0][0], q, esD, escD);
        }
    } else {  // boundary chunk: uniform-predicated
        for (int r = 0; r < 8; ++r) {
            const int s0 = 2 * r, s1 = s0 + 1;
            if (s0 < nA) estep(A, Ba, &emS[s0][0],      q, esA, escA);
            if (s0 < nB) estep(A, Bb, &emS[16 + s0][0], q, esB, escB);
            if (s0 < nC) estep(A, Bc, &emS[32 + s0][0], q, esC, escC);
            if (s0 < nD) estep(A, Bd, &emS[48 + s0][0], q, esD, escD);
            if (s1 < nA) estep(A, Ba, &emS[s1][0],      q, esA, escA);
            if (s1 < nB) estep(A, Bb, &emS[16 + s1][0], q, esB, escB);
            if (s1 < nC) estep(A, Bc, &emS[32 + s1][0], q, esC, escC);
            if (s1 < nD) estep(A, Bd, &emS[48 + s1][0], q, esD, escD);
        }
    }

    // ---- merge level 1: P1 = Hb*Ha, P2 = Hd*Hc (parallel) ----
    if (l == 0) { ebuf[w] = esB; ebuf[4 + w] = esD; }
    __syncthreads();
    const int eBmax = max(max(ebuf[0], ebuf[1]), max(ebuf[2], ebuf[3]));
    const int eDmax = max(max(ebuf[4], ebuf[5]), max(ebuf[6], ebuf[7]));
    {
        _Float16 sB = (_Float16)ldexpf(1.f, esB - eBmax);
        _Float16 sD = (_Float16)ldexpf(1.f, esD - eDmax);
        h4 s4B = {sB, sB, sB, sB}, s4D = {sD, sD, sD, sD};
#pragma unroll
        for (int ks = 0; ks < 4; ++ks) {
            h4 vb = Bb[ks] * s4B;
            h4 vd = Bd[ks] * s4D;
#pragma unroll
            for (int jj = 0; jj < 4; ++jj) {
                mldB[(16 * ks + 4 * q + jj) * MSTR + ncol] = vb[jj];
                mldD[(16 * ks + 4 * q + jj) * MSTR + ncol] = vd[jj];
            }
        }
    }
    __syncthreads();
    h4 AHb[4][4], AHd[4][4];
#pragma unroll
    for (int mt = 0; mt < 4; ++mt)
#pragma unroll
        for (int ks = 0; ks < 4; ++ks) {
            AHb[mt][ks] = *(const h4*)(mldB + (16 * mt + n16) * MSTR + 16 * ks + 4 * q);
            AHd[mt][ks] = *(const h4*)(mldD + (16 * mt + n16) * MSTR + 16 * ks + 4 * q);
        }
    v4f z = {0.f, 0.f, 0.f, 0.f};
    v4f P1[4], P2[4];
#pragma unroll
    for (int mt = 0; mt < 4; ++mt) {
        v4f a = __builtin_amdgcn_mfma_f32_16x16x16f16(AHb[mt][0], Ba[0], z, 0, 0, 0);
        a = __builtin_amdgcn_mfma_f32_16x16x16f16(AHb[mt][1], Ba[1], a, 0, 0, 0);
        v4f b = __builtin_amdgcn_mfma_f32_16x16x16f16(AHb[mt][2], Ba[2], z, 0, 0, 0);
        b = __builtin_amdgcn_mfma_f32_16x16x16f16(AHb[mt][3], Ba[3], b, 0, 0, 0);
        P1[mt] = a + b;
        v4f a2 = __builtin_amdgcn_mfma_f32_16x16x16f16(AHd[mt][0], Bc[0], z, 0, 0, 0);
        a2 = __builtin_amdgcn_mfma_f32_16x16x16f16(AHd[mt][1], Bc[1], a2, 0, 0, 0);
        v4f b2 = __builtin_amdgcn_mfma_f32_16x16x16f16(AHd[mt][2], Bc[2], z, 0, 0, 0);
        b2 = __builtin_amdgcn_mfma_f32_16x16x16f16(AHd[mt][3], Bc[3], b2, 0, 0, 0);
        P2[mt] = a2 + b2;
    }
    float m1 = 0.f, m2 = 0.f;
#pragma unroll
    for (int mt = 0; mt < 4; ++mt) {
        m1 = fmaxf(m1, fmaxf(fmaxf(P1[mt].x, P1[mt].y), fmaxf(P1[mt].z, P1[mt].w)));
        m2 = fmaxf(m2, fmaxf(fmaxf(P2[mt].x, P2[mt].y), fmaxf(P2[mt].z, P2[mt].w)));
    }
#pragma unroll
    for (int m = 1; m < 64; m <<= 1) {
        m1 = fmaxf(m1, __shfl_xor(m1, m, 64));
        m2 = fmaxf(m2, __shfl_xor(m2, m, 64));
    }
    unsigned u1 = (unsigned)__builtin_amdgcn_readfirstlane((int)__float_as_uint(m1));
    unsigned u2 = (unsigned)__builtin_amdgcn_readfirstlane((int)__float_as_uint(m2));
    const int e1c = u1 ? (int)((u1 >> 23) & 255u) - 127 : 0;
    const int e2c = u2 ? (int)((u2 >> 23) & 255u) - 127 : 0;
    const int e1 = esA + eBmax + e1c;
    const int e2 = esC + eDmax + e2c;
    h4 P1h[4], P2h[4];
    {
        float s1f = __uint_as_float((unsigned)(127 - e1c) << 23);
        float s2f = __uint_as_float((unsigned)(127 - e2c) << 23);
#pragma unroll
        for (int mt = 0; mt < 4; ++mt) {
            v4f q1 = P1[mt] * s1f;
            v4f q2 = P2[mt] * s2f;
            H4u ua, ub;
            ua.p.lo = __builtin_amdgcn_cvt_pkrtz(q1.x, q1.y);
            ua.p.hi = __builtin_amdgcn_cvt_pkrtz(q1.z, q1.w);
            ub.p.lo = __builtin_amdgcn_cvt_pkrtz(q2.x, q2.y);
            ub.p.hi = __builtin_amdgcn_cvt_pkrtz(q2.z, q2.w);
            P1h[mt] = ua.v;
            P2h[mt] = ub.v;
        }
    }

    // ---- merge level 2: R = P2 * P1 ----
    if (l == 0) ebuf[8 + w] = e2;
    __syncthreads();
    const int e2max = max(max(ebuf[8], ebuf[9]), max(ebuf[10], ebuf[11]));
    {
        _Float16 s2 = (_Float16)ldexpf(1.f, e2 - e2max);
        h4 s4 = {s2, s2, s2, s2};
#pragma unroll
        for (int mt = 0; mt < 4; ++mt) {
            h4 v = P2h[mt] * s4;
#pragma unroll
            for (int jj = 0; jj < 4; ++jj)
                mldB[(16 * mt + 4 * q + jj) * MSTR + ncol] = v[jj];
        }
    }
    __syncthreads();
    h4 AHp[4][4];
#pragma unroll
    for (int mt = 0; mt < 4; ++mt)
#pragma unroll
        for (int ks = 0; ks < 4; ++ks)
            AHp[mt][ks] = *(const h4*)(mldB + (16 * mt + n16) * MSTR + 16 * ks + 4 * q);
    h4 Rf[4];
#pragma unroll
    for (int mt = 0; mt < 4; ++mt) {
        v4f a = __builtin_amdgcn_mfma_f32_16x16x16f16(AHp[mt][0], P1h[0], z, 0, 0, 0);
        a = __builtin_amdgcn_mfma_f32_16x16x16f16(AHp[mt][1], P1h[1], a, 0, 0, 0);
        v4f b = __builtin_amdgcn_mfma_f32_16x16x16f16(AHp[mt][2], P1h[2], z, 0, 0, 0);
        b = __builtin_amdgcn_mfma_f32_16x16x16f16(AHp[mt][3], P1h[3], b, 0, 0, 0);
        v4f d = a + b;
        H4u u;
        u.p.lo = __builtin_amdgcn_cvt_pkrtz(d.x, d.y);
        u.p.hi = __builtin_amdgcn_cvt_pkrtz(d.z, d.w);
        Rf[mt] = u.v;
    }
    __syncthreads();  // mldD reads (AHd) done; reuse for output staging
#pragma unroll
    for (int mt = 0; mt < 4; ++mt)
#pragma unroll
        for (int jj = 0; jj < 4; ++jj)
            mldD[(16 * mt + 4 * q + jj) * MSTR + ncol] = Rf[mt][jj];
    __syncthreads();
    {
        const size_t base_ = ((size_t)chain * CC + c) * 4096;
        int r = tid >> 2, cb = tid & 3;
        const uint4* src = (const uint4*)(mldD + r * MSTR + cb * 16);
        uint4* dst = (uint4*)(Pg + base_ + r * TT + cb * 16);
        dst[0] = src[0];
        dst[1] = src[1];
    }
    if (q == 0) Eg[(chain * CC + c) * TT + ncol] = e1 + e2max;
}

// ---------------- combine helpers (r12-verified) ----------------
__device__ __forceinline__ int wimax64(int v) {
#pragma unroll
    for (int m = 1; m < 64; m <<= 1) v = max(v, __shfl_xor(v, m, 64));
    return v;
}
__device__ __forceinline__ float wfmax64(float v) {
#pragma unroll
    for (int m = 1; m < 64; m <<= 1) v = fmaxf(v, __shfl_xor(v, m, 64));
    return v;
}
__device__ __forceinline__ float wfsum64(float v) {
#pragma unroll
    for (int m = 1; m < 64; m <<= 1) v += __shfl_xor(v, m, 64);
    return v;
}
__device__ __forceinline__ int fexp(float m) {
    unsigned u = (unsigned)__builtin_amdgcn_readfirstlane((int)__float_as_uint(m));
    return u ? (int)((u >> 23) & 255u) - 127 : 0;
}
__device__ __forceinline__ void mm64(const h4 (&A)[4][4], const h4 (&B)[4], v4f (&D)[4]) {
    v4f z = {0.f, 0.f, 0.f, 0.f};
#pragma unroll
    for (int mt = 0; mt < 4; ++mt) {
        v4f a = __builtin_amdgcn_mfma_f32_16x16x16f16(A[mt][0], B[0], z, 0, 0, 0);
        a = __builtin_amdgcn_mfma_f32_16x16x16f16(A[mt][1], B[1], a, 0, 0, 0);
        v4f b = __builtin_amdgcn_mfma_f32_16x16x16f16(A[mt][2], B[2], z, 0, 0, 0);
        b = __builtin_amdgcn_mfma_f32_16x16x16f16(A[mt][3], B[3], b, 0, 0, 0);
        D[mt] = a + b;
    }
}
__device__ __forceinline__ float dmax16(const v4f (&D)[4]) {
    float m = 0.f;
#pragma unroll
    for (int mt = 0; mt < 4; ++mt)
        m = fmaxf(m, fmaxf(fmaxf(D[mt].x, D[mt].y), fmaxf(D[mt].z, D[mt].w)));
    return m;
}
__device__ __forceinline__ void prodG(const unsigned short* __restrict__ PgC, int cA, int cB,
                                      const float* __restrict__ sAt,
                                      int n16, int q, int ncol, v4f (&D)[4]) {
    const _Float16* Ap = (const _Float16*)PgC + cA * 4096;
    const _Float16* Bp = (const _Float16*)PgC + cB * 4096;
    h4 Af[4][4];
#pragma unroll
    for (int mt = 0; mt < 4; ++mt)
#pragma unroll
        for (int ks = 0; ks < 4; ++ks) {
            h4 raw = *(const h4*)(Ap + (16 * mt + n16) * TT + 16 * ks + 4 * q);
            v4f s = *(const v4f*)(sAt + 16 * ks + 4 * q);
            h4 a;
#pragma unroll
            for (int e = 0; e < 4; ++e) a[e] = (_Float16)((float)raw[e] * s[e]);
            Af[mt][ks] = a;
        }
    h4 Bf[4];
#pragma unroll
    for (int ks = 0; ks < 4; ++ks) {
        h4 b;
#pragma unroll
        for (int j = 0; j < 4; ++j) b[j] = Bp[(16 * ks + 4 * q + j) * TT + ncol];
        Bf[ks] = b;
    }
    mm64(Af, Bf, D);
}

// ---------------- combine: merge tree + final contraction + gold ----------------
__global__ __launch_bounds__(256, 1)
void crf_combine(const float* __restrict__ feats, const float* __restrict__ trans,
                 const int* __restrict__ mask, const int* __restrict__ tags,
                 const unsigned short* __restrict__ Pg, const int* __restrict__ Eg,
                 float* __restrict__ out) {
    __shared__ __align__(16) _Float16 stg[TT * MSTR];
    __shared__ __align__(16) float sA[4][TT];
    __shared__ __align__(16) float wend[TT];
    __shared__ int eodd[4];
    __shared__ int ib0[4], ib1[4], ib2[4], ib3[4];
    __shared__ float redf[4], gred[4];

    const int chain = blockIdx.x;
    const int tid = threadIdx.x;
    const int w = tid >> 6, l = tid & 63;
    const int n16 = l & 15, q = l >> 4;
    const int ncol = 16 * w + n16;
    const unsigned short* PgC = Pg + (size_t)chain * CC * 4096;
    const int* EgC = Eg + chain * CC * TT;

    // chain length L (per-wave, redundant)
    int msum = 0;
#pragma unroll
    for (int k = 0; k < 8; ++k) msum += mask[chain * SS + 64 * k + l];
#pragma unroll
    for (int m = 1; m < 64; m <<= 1) msum += __shfl_xor(msum, m, 64);
    const int L = msum;

    // gold partial: 2 positions per thread
    float g = 0.f;
#pragma unroll
    for (int rep = 0; rep < 2; ++rep) {
        int t = tid + rep * 256;
        if (t < L) {
            int cur = tags[chain * SS + t];
            int prev = t ? tags[chain * SS + t - 1] : START_TAG;
            g += feats[(size_t)chain * SS * TT + (size_t)t * TT + cur] + trans[prev * TT + cur];
        }
    }
    g = wfsum64(g);
    if (l == 0) gred[w] = g;

    // fold tables for odd chunks
    {
        int e1 = EgC[(2 * w + 1) * TT + l];
        int em = wimax64(e1);
        if (l == 0) eodd[w] = em;
        sA[w][l] = ldexpf(1.f, e1 - em);
    }
    if (tid < TT) wend[tid] = expf(trans[tid * TT + END_TAG]);
    __syncthreads();  // B1

    const float* f0 = feats + (size_t)chain * SS * TT;
    float pl = f0[l] + trans[START_TAG * TT + l];
    float M0 = wfmax64(pl);
    float pc = f0[ncol] + trans[START_TAG * TT + ncol];
    float p0c = __builtin_amdgcn_exp2f((pc - M0) * LOG2E_F);

    const int eqB0 = EgC[0 * TT + ncol];
    const int eqB1 = EgC[2 * TT + ncol];
    const int eqB2 = EgC[4 * TT + ncol];
    const int eqB3 = EgC[6 * TT + ncol];
    const int eo0 = eodd[0], eo1 = eodd[1], eo2 = eodd[2], eo3 = eodd[3];

    v4f D[4];
    // ---- Q1 = H3*H2 ----
    prodG(PgC, 3, 2, &sA[1][0], n16, q, ncol, D);
    int ec1 = fexp(wfmax64(dmax16(D)));
    int eq1 = eqB1 + eo1 + ec1;
    int eq1m = wimax64(eq1);
    if (l == 0) ib0[w] = eq1m;
    __syncthreads();  // B2
    const int emax1 = max(max(ib0[0], ib0[1]), max(ib0[2], ib0[3]));
    {
        float sc = ldexpf(1.f, eqB1 + eo1 - emax1);
#pragma unroll
        for (int mt = 0; mt < 4; ++mt)
#pragma unroll
            for (int jj = 0; jj < 4; ++jj)
                stg[(16 * mt + 4 * q + jj) * MSTR + ncol] = (_Float16)(D[mt][jj] * sc);
    }
    // ---- Q0 = H1*H0 ----
    v4f D0[4];
    prodG(PgC, 1, 0, &sA[0][0], n16, q, ncol, D0);
    int ec0 = fexp(wfmax64(dmax16(D0)));
    int eq0 = eqB0 + eo0 + ec0;
    h4 Q0h[4];
    {
        float s0 = ldexpf(1.f, -ec0);
#pragma unroll
        for (int mt = 0; mt < 4; ++mt) {
            v4f qv = D0[mt] * s0;
            H4u u;
            u.p.lo = __builtin_amdgcn_cvt_pkrtz(qv.x, qv.y);
            u.p.hi = __builtin_amdgcn_cvt_pkrtz(qv.z, qv.w);
            Q0h[mt] = u.v;
        }
    }
    __syncthreads();  // B3: stg(Q1) ready
    h4 AH[4][4];
#pragma unroll
    for (int mt = 0; mt < 4; ++mt)
#pragma unroll
        for (int ks = 0; ks < 4; ++ks)
            AH[mt][ks] = *(const h4*)(stg + (16 * mt + n16) * MSTR + 16 * ks + 4 * q);
    v4f Dlo[4];
    mm64(AH, Q0h, Dlo);
    int eclo = fexp(wfmax64(dmax16(Dlo)));
    int eqlo = eq0 + emax1 + eclo;
    h4 Ploh[4];
    {
        float sl = ldexpf(1.f, -eclo);
#pragma unroll
        for (int mt = 0; mt < 4; ++mt) {
            v4f qv = Dlo[mt] * sl;
            H4u u;
            u.p.lo = __builtin_amdgcn_cvt_pkrtz(qv.x, qv.y);
            u.p.hi = __builtin_amdgcn_cvt_pkrtz(qv.z, qv.w);
            Ploh[mt] = u.v;
        }
    }
    // ---- Q3 = H7*H6 ----
    prodG(PgC, 7, 6, &sA[3][0], n16, q, ncol, D);
    int ec3 = fexp(wfmax64(dmax16(D)));
    int eq3 = eqB3 + eo3 + ec3;
    int eq3m = wimax64(eq3);
    if (l == 0) ib1[w] = eq3m;
    __syncthreads();  // B4
    const int emax3 = max(max(ib1[0], ib1[1]), max(ib1[2], ib1[3]));
    {
        float sc = ldexpf(1.f, eqB3 + eo3 - emax3);
#pragma unroll
        for (int mt = 0; mt < 4; ++mt)
#pragma unroll
            for (int jj = 0; jj < 4; ++jj)
                stg[(16 * mt + 4 * q + jj) * MSTR + ncol] = (_Float16)(D[mt][jj] * sc);
    }
    // ---- Q2 = H5*H4 ----
    v4f D2[4];
    prodG(PgC, 5, 4, &sA[2][0], n16, q, ncol, D2);
    int ec2 = fexp(wfmax64(dmax16(D2)));
    int eq2 = eqB2 + eo2 + ec2;
    h4 Q2h[4];
    {
        float s2 = ldexpf(1.f, -ec2);
#pragma unroll
        for (int mt = 0; mt < 4; ++mt) {
            v4f qv = D2[mt] * s2;
            H4u u;
            u.p.lo = __builtin_amdgcn_cvt_pkrtz(qv.x, qv.y);
            u.p.hi = __builtin_amdgcn_cvt_pkrtz(qv.z, qv.w);
            Q2h[mt] = u.v;
        }
    }
    __syncthreads();  // B5: stg(Q3) ready
#pragma unroll
    for (int mt = 0; mt < 4; ++mt)
#pragma unroll
        for (int ks = 0; ks < 4; ++ks)
            AH[mt][ks] = *(const h4*)(stg + (16 * mt + n16) * MSTR + 16 * ks + 4 * q);
    v4f Dhi[4];
    mm64(AH, Q2h, Dhi);
    int echi = fexp(wfmax64(dmax16(Dhi)));
    int eqhi = eq2 + emax3 + echi;
    int eqhim = wimax64(eqhi);
    if (l == 0) ib2[w] = eqhim;
    __syncthreads();  // B6
    const int emaxhi = max(max(ib2[0], ib2[1]), max(ib2[2], ib2[3]));
    {
        float sc = ldexpf(1.f, eq2 + emax3 - emaxhi);
#pragma unroll
        for (int mt = 0; mt < 4; ++mt)
#pragma unroll
            for (int jj = 0; jj < 4; ++jj)
                stg[(16 * mt + 4 * q + jj) * MSTR + ncol] = (_Float16)(Dhi[mt][jj] * sc);
    }
    __syncthreads();  // B7: stg(P_hi) ready
#pragma unroll
    for (int mt = 0; mt < 4; ++mt)
#pragma unroll
        for (int ks = 0; ks < 4; ++ks)
            AH[mt][ks] = *(const h4*)(stg + (16 * mt + n16) * MSTR + 16 * ks + 4 * q);
    v4f DR[4];
    mm64(AH, Ploh, DR);

    // ---- final contraction: fwd = log( wend^T R p0 ) ----
    float zsum = 0.f;
#pragma unroll
    for (int mt = 0; mt < 4; ++mt) {
        v4f wv = *(const v4f*)(wend + 16 * mt + 4 * q);
        zsum += wv.x * DR[mt].x + wv.y * DR[mt].y + wv.z * DR[mt].z + wv.w * DR[mt].w;
    }
    zsum += __shfl_xor(zsum, 16, 64);
    zsum += __shfl_xor(zsum, 32, 64);
    float val = zsum * p0c;
    int ex = eqlo + emaxhi;
    int exm = wimax64(ex);
    float contrib = (q == 0) ? ldexpf(val, ex - exm) : 0.f;
    float Sw = wfsum64(contrib);
    if (l == 0) { redf[w] = Sw; ib3[w] = exm; }
    __syncthreads();  // B8
    if (tid == 0) {
        int gmax = max(max(ib3[0], ib3[1]), max(ib3[2], ib3[3]));
        float tot = 0.f;
#pragma unroll
        for (int p = 0; p < 4; ++p) tot += ldexpf(redf[p], ib3[p] - gmax);
        float fwd = logf(tot) + (float)gmax * LN2_F + M0;
        float gold = gred[0] + gred[1] + gred[2] + gred[3] +
                     trans[tags[chain * SS + L - 1] * TT + END_TAG];
        atomicAdd(out, fwd - gold);
    }
}

extern "C" void kernel_launch(void* const* d_in, const int* in_sizes, int n_in,
                              void* d_out, int out_size, void* d_ws, size_t ws_size,
                              hipStream_t stream) {
    const float* feats = (const float*)d_in[0];
    const float* trans = (const float*)d_in[1];
    const int*   mask  = (const int*)d_in[2];
    const int*   tags  = (const int*)d_in[3];
    float* out = (float*)d_out;
    unsigned short* Pg = (unsigned short*)d_ws;
    int*       Eg = (int*)((char*)d_ws + WS_ECOL_OFF);

    crf_chunks<<<dim3(64 * CC), dim3(256), 0, stream>>>(feats, trans, mask, Pg, Eg, out);
    crf_combine<<<dim3(64), dim3(256), 0, stream>>>(feats, trans, mask, tags, Pg, Eg, out);
}

// Round 5
// 114.463 us; speedup vs baseline: 1.6387x; 1.0667x over previous
//
#include <hip/hip_runtime.h>

// CRF NLL on MI355X — round 15: occupancy + cheap combine.
// K1 (chunks): CC=16 chunks of 32 steps (4 sub-chains x 8 steps, same 4-way
//   in-wave ILP), grid 1024 = 4 blocks/CU = 4 waves/SIMD (was 2) — fills the
//   ~45% dependency-stall seen at 2 waves/SIMD. Burst-LDS emissions kept.
//   Merge = r11/r14-verified 2-level tree. Pg = 8 MB workspace.
// K2 (combine): per-chain pipelined matvec chain. Lane l owns row l; per
//   chunk: prefetched 128B row load + 64-FMA dot vs exponent-folded x in
//   wave-local LDS + wave-max renorm. No barriers in loop, serial depth
//   16 x ~400cy. Gold parallel over 256 threads.

#define SS 512
#define TT 64
#define CC 16
#define KCH 32
#define START_TAG 62
#define END_TAG 63
#define LOG2E_F 1.44269504088896340736f
#define LN2_F 0.69314718055994530942f

#define WS_ECOL_OFF 8388608   // Pg: 64*16*4096*2B = 8 MB
#define MSTR 72               // merge-LDS row stride in halfs

typedef float v4f __attribute__((ext_vector_type(4)));
typedef _Float16 h4 __attribute__((ext_vector_type(4)));
typedef __fp16 c2 __attribute__((ext_vector_type(2)));
union H4u { h4 v; struct { c2 lo, hi; } p; };

// ---------------- per-step core: LDS-emission variant (r14) ----------------
__device__ __forceinline__ void estep(const h4 (&A)[4][4], h4 (&B)[4],
                                      const float* __restrict__ emrow,
                                      int q, int& esum, int& esc) {
    v4f z = {0.f, 0.f, 0.f, 0.f};
    v4f D[4];
#pragma unroll
    for (int mt = 0; mt < 4; ++mt) {
        v4f a = __builtin_amdgcn_mfma_f32_16x16x16f16(A[mt][0], B[0], z, 0, 0, 0);
        a = __builtin_amdgcn_mfma_f32_16x16x16f16(A[mt][1], B[1], a, 0, 0, 0);
        v4f b = __builtin_amdgcn_mfma_f32_16x16x16f16(A[mt][2], B[2], z, 0, 0, 0);
        b = __builtin_amdgcn_mfma_f32_16x16x16f16(A[mt][3], B[3], b, 0, 0, 0);
        D[mt] = a + b;
    }
    esum += esc;
    float scf = __uint_as_float((unsigned)(127 - esc) << 23);
    v4f qs[4];
#pragma unroll
    for (int mt = 0; mt < 4; ++mt) {
        v4f em = *(const v4f*)(emrow + 16 * mt + 4 * q);
        qs[mt] = D[mt] * (em * scf);
    }
#pragma unroll
    for (int mt = 0; mt < 4; ++mt) {
        H4u u;
        u.p.lo = __builtin_amdgcn_cvt_pkrtz(qs[mt].x, qs[mt].y);
        u.p.hi = __builtin_amdgcn_cvt_pkrtz(qs[mt].z, qs[mt].w);
        B[mt] = u.v;
    }
    unsigned u0 = (unsigned)__builtin_amdgcn_readfirstlane((int)__float_as_uint(qs[0].x));
    esc = (int)((u0 >> 23) & 255u) - 127;
}

// ---------------- chunk kernel: 4 sub-chains x 8 steps, LDS emissions ----------------
__global__ __launch_bounds__(256, 4)
void crf_chunks(const float* __restrict__ feats, const float* __restrict__ trans,
                const int* __restrict__ mask, unsigned short* __restrict__ Pg,
                int* __restrict__ Eg, float* __restrict__ out) {
    __shared__ __align__(16) float emS[KCH][TT];          // 8 KB emissions
    __shared__ __align__(16) _Float16 mldB[TT * MSTR];
    __shared__ __align__(16) _Float16 mldD[TT * MSTR];
    __shared__ int ebuf[12];

    const int blk = blockIdx.x;
    const int chain = blk >> 4, c = blk & 15;
    const int tid = threadIdx.x;
    const int w = tid >> 6, l = tid & 63;
    const int n16 = l & 15, q = l >> 4;
    const int ncol = 16 * w + n16;

    if (blk == 0 && tid == 0) out[0] = 0.f;

    // A = E^T stationary frags from trans
    h4 A[4][4];
#pragma unroll
    for (int mt = 0; mt < 4; ++mt)
#pragma unroll
        for (int ks = 0; ks < 4; ++ks) {
            h4 a;
#pragma unroll
            for (int e = 0; e < 4; ++e)
                a[e] = (_Float16)__builtin_amdgcn_exp2f(
                    trans[(16 * ks + 4 * q + e) * TT + 16 * mt + n16] * LOG2E_F);
            A[mt][ks] = a;
        }

    // chain length L
    const int* mp = mask + chain * SS;
    int msum = 0;
#pragma unroll
    for (int k = 0; k < 8; ++k) msum += mp[k * 64 + l];
#pragma unroll
    for (int s_ = 1; s_ < 64; s_ <<= 1) msum += __shfl_xor(msum, s_, 64);
    const int L = msum;

    const int t0a = 1 + KCH * c;
    const int base = (L - 1) - KCH * c;
    int nA = base < 0 ? 0 : (base > 8 ? 8 : base);
    int nB = base - 8 < 0 ? 0 : (base - 8 > 8 ? 8 : base - 8);
    int nC = base - 16 < 0 ? 0 : (base - 16 > 8 ? 8 : base - 16);
    int nD = base - 24 < 0 ? 0 : (base - 24 > 8 ? 8 : base - 24);

    // ---- burst-load emissions: 32 timesteps x 64 tags, exp2'd into LDS ----
    const float* fbase = feats + (size_t)chain * SS * TT;
#pragma unroll
    for (int k = 0; k < 2; ++k) {
        int idx = tid + 256 * k;      // 0..511
        int row = idx >> 4;           // 0..31
        int seg = idx & 15;           // 16B segment
        int t = t0a + row;
        t = t < SS ? t : SS - 1;
        v4f v = *(const v4f*)(fbase + (size_t)t * TT + 4 * seg);
        v4f e;
        e.x = __builtin_amdgcn_exp2f(v.x * LOG2E_F);
        e.y = __builtin_amdgcn_exp2f(v.y * LOG2E_F);
        e.z = __builtin_amdgcn_exp2f(v.z * LOG2E_F);
        e.w = __builtin_amdgcn_exp2f(v.w * LOG2E_F);
        *(v4f*)(&emS[row][4 * seg]) = e;
    }

    // identity inits
    h4 Ba[4], Bb[4], Bc[4], Bd[4];
#pragma unroll
    for (int ks = 0; ks < 4; ++ks) {
        h4 b;
#pragma unroll
        for (int jj = 0; jj < 4; ++jj)
            b[jj] = (_Float16)((16 * ks + 4 * q + jj == ncol) ? 1.f : 0.f);
        Ba[ks] = b; Bb[ks] = b; Bc[ks] = b; Bd[ks] = b;
    }
    __syncthreads();  // emS ready

    int esA = 0, escA = 0, esB = 0, escB = 0;
    int esC = 0, escC = 0, esD = 0, escD = 0;

    if (nD == 8) {  // all four sub-chains full: branch-free hot path
        for (int r = 0; r < 4; ++r) {
            const int s0 = 2 * r, s1 = s0 + 1;
            estep(A, Ba, &emS[s0][0],      q, esA, escA);
            estep(A, Bb, &emS[8 + s0][0],  q, esB, escB);
            estep(A, Bc, &emS[16 + s0][0], q, esC, escC);
            estep(A, Bd, &emS[24 + s0][0], q, esD, escD);
            estep(A, Ba, &emS[s1][0],      q, esA, escA);
            estep(A, Bb, &emS[8 + s1][0],  q, esB, escB);
            estep(A, Bc, &emS[16 + s1][0], q, esC, escC);
            estep(A, Bd, &emS[24 + s1][0], q, esD, escD);
        }
    } else {  // boundary chunk: uniform-predicated
        for (int r = 0; r < 4; ++r) {
            const int s0 = 2 * r, s1 = s0 + 1;
            if (s0 < nA) estep(A, Ba, &emS[s0][0],      q, esA, escA);
            if (s0 < nB) estep(A, Bb, &emS[8 + s0][0],  q, esB, escB);
            if (s0 < nC) estep(A, Bc, &emS[16 + s0][0], q, esC, escC);
            if (s0 < nD) estep(A, Bd, &emS[24 + s0][0], q, esD, escD);
            if (s1 < nA) estep(A, Ba, &emS[s1][0],      q, esA, escA);
            if (s1 < nB) estep(A, Bb, &emS[8 + s1][0],  q, esB, escB);
            if (s1 < nC) estep(A, Bc, &emS[16 + s1][0], q, esC, escC);
            if (s1 < nD) estep(A, Bd, &emS[24 + s1][0], q, esD, escD);
        }
    }

    // ---- merge level 1: P1 = Hb*Ha, P2 = Hd*Hc (parallel) ----
    if (l == 0) { ebuf[w] = esB; ebuf[4 + w] = esD; }
    __syncthreads();
    const int eBmax = max(max(ebuf[0], ebuf[1]), max(ebuf[2], ebuf[3]));
    const int eDmax = max(max(ebuf[4], ebuf[5]), max(ebuf[6], ebuf[7]));
    {
        _Float16 sB = (_Float16)ldexpf(1.f, esB - eBmax);
        _Float16 sD = (_Float16)ldexpf(1.f, esD - eDmax);
        h4 s4B = {sB, sB, sB, sB}, s4D = {sD, sD, sD, sD};
#pragma unroll
        for (int ks = 0; ks < 4; ++ks) {
            h4 vb = Bb[ks] * s4B;
            h4 vd = Bd[ks] * s4D;
#pragma unroll
            for (int jj = 0; jj < 4; ++jj) {
                mldB[(16 * ks + 4 * q + jj) * MSTR + ncol] = vb[jj];
                mldD[(16 * ks + 4 * q + jj) * MSTR + ncol] = vd[jj];
            }
        }
    }
    __syncthreads();
    h4 AHb[4][4], AHd[4][4];
#pragma unroll
    for (int mt = 0; mt < 4; ++mt)
#pragma unroll
        for (int ks = 0; ks < 4; ++ks) {
            AHb[mt][ks] = *(const h4*)(mldB + (16 * mt + n16) * MSTR + 16 * ks + 4 * q);
            AHd[mt][ks] = *(const h4*)(mldD + (16 * mt + n16) * MSTR + 16 * ks + 4 * q);
        }
    v4f z = {0.f, 0.f, 0.f, 0.f};
    v4f P1[4], P2[4];
#pragma unroll
    for (int mt = 0; mt < 4; ++mt) {
        v4f a = __builtin_amdgcn_mfma_f32_16x16x16f16(AHb[mt][0], Ba[0], z, 0, 0, 0);
        a = __builtin_amdgcn_mfma_f32_16x16x16f16(AHb[mt][1], Ba[1], a, 0, 0, 0);
        v4f b = __builtin_amdgcn_mfma_f32_16x16x16f16(AHb[mt][2], Ba[2], z, 0, 0, 0);
        b = __builtin_amdgcn_mfma_f32_16x16x16f16(AHb[mt][3], Ba[3], b, 0, 0, 0);
        P1[mt] = a + b;
        v4f a2 = __builtin_amdgcn_mfma_f32_16x16x16f16(AHd[mt][0], Bc[0], z, 0, 0, 0);
        a2 = __builtin_amdgcn_mfma_f32_16x16x16f16(AHd[mt][1], Bc[1], a2, 0, 0, 0);
        v4f b2 = __builtin_amdgcn_mfma_f32_16x16x16f16(AHd[mt][2], Bc[2], z, 0, 0, 0);
        b2 = __builtin_amdgcn_mfma_f32_16x16x16f16(AHd[mt][3], Bc[3], b2, 0, 0, 0);
        P2[mt] = a2 + b2;
    }
    float m1 = 0.f, m2 = 0.f;
#pragma unroll
    for (int mt = 0; mt < 4; ++mt) {
        m1 = fmaxf(m1, fmaxf(fmaxf(P1[mt].x, P1[mt].y), fmaxf(P1[mt].z, P1[mt].w)));
        m2 = fmaxf(m2, fmaxf(fmaxf(P2[mt].x, P2[mt].y), fmaxf(P2[mt].z, P2[mt].w)));
    }
#pragma unroll
    for (int m = 1; m < 64; m <<= 1) {
        m1 = fmaxf(m1, __shfl_xor(m1, m, 64));
        m2 = fmaxf(m2, __shfl_xor(m2, m, 64));
    }
    unsigned u1 = (unsigned)__builtin_amdgcn_readfirstlane((int)__float_as_uint(m1));
    unsigned u2 = (unsigned)__builtin_amdgcn_readfirstlane((int)__float_as_uint(m2));
    const int e1c = u1 ? (int)((u1 >> 23) & 255u) - 127 : 0;
    const int e2c = u2 ? (int)((u2 >> 23) & 255u) - 127 : 0;
    const int e1 = esA + eBmax + e1c;
    const int e2 = esC + eDmax + e2c;
    h4 P1h[4], P2h[4];
    {
        float s1f = __uint_as_float((unsigned)(127 - e1c) << 23);
        float s2f = __uint_as_float((unsigned)(127 - e2c) << 23);
#pragma unroll
        for (int mt = 0; mt < 4; ++mt) {
            v4f q1 = P1[mt] * s1f;
            v4f q2 = P2[mt] * s2f;
            H4u ua, ub;
            ua.p.lo = __builtin_amdgcn_cvt_pkrtz(q1.x, q1.y);
            ua.p.hi = __builtin_amdgcn_cvt_pkrtz(q1.z, q1.w);
            ub.p.lo = __builtin_amdgcn_cvt_pkrtz(q2.x, q2.y);
            ub.p.hi = __builtin_amdgcn_cvt_pkrtz(q2.z, q2.w);
            P1h[mt] = ua.v;
            P2h[mt] = ub.v;
        }
    }

    // ---- merge level 2: R = P2 * P1 ----
    if (l == 0) ebuf[8 + w] = e2;
    __syncthreads();
    const int e2max = max(max(ebuf[8], ebuf[9]), max(ebuf[10], ebuf[11]));
    {
        _Float16 s2 = (_Float16)ldexpf(1.f, e2 - e2max);
        h4 s4 = {s2, s2, s2, s2};
#pragma unroll
        for (int mt = 0; mt < 4; ++mt) {
            h4 v = P2h[mt] * s4;
#pragma unroll
            for (int jj = 0; jj < 4; ++jj)
                mldB[(16 * mt + 4 * q + jj) * MSTR + ncol] = v[jj];
        }
    }
    __syncthreads();
    h4 AHp[4][4];
#pragma unroll
    for (int mt = 0; mt < 4; ++mt)
#pragma unroll
        for (int ks = 0; ks < 4; ++ks)
            AHp[mt][ks] = *(const h4*)(mldB + (16 * mt + n16) * MSTR + 16 * ks + 4 * q);
    h4 Rf[4];
#pragma unroll
    for (int mt = 0; mt < 4; ++mt) {
        v4f a = __builtin_amdgcn_mfma_f32_16x16x16f16(AHp[mt][0], P1h[0], z, 0, 0, 0);
        a = __builtin_amdgcn_mfma_f32_16x16x16f16(AHp[mt][1], P1h[1], a, 0, 0, 0);
        v4f b = __builtin_amdgcn_mfma_f32_16x16x16f16(AHp[mt][2], P1h[2], z, 0, 0, 0);
        b = __builtin_amdgcn_mfma_f32_16x16x16f16(AHp[mt][3], P1h[3], b, 0, 0, 0);
        v4f d = a + b;
        H4u u;
        u.p.lo = __builtin_amdgcn_cvt_pkrtz(d.x, d.y);
        u.p.hi = __builtin_amdgcn_cvt_pkrtz(d.z, d.w);
        Rf[mt] = u.v;
    }
    __syncthreads();  // mldD reads done; reuse for output staging
#pragma unroll
    for (int mt = 0; mt < 4; ++mt)
#pragma unroll
        for (int jj = 0; jj < 4; ++jj)
            mldD[(16 * mt + 4 * q + jj) * MSTR + ncol] = Rf[mt][jj];
    __syncthreads();
    {
        const size_t base_ = ((size_t)chain * CC + c) * 4096;
        int r = tid >> 2, cb = tid & 3;
        const uint4* src = (const uint4*)(mldD + r * MSTR + cb * 16);
        uint4* dst = (uint4*)(Pg + base_ + r * TT + cb * 16);
        dst[0] = src[0];
        dst[1] = src[1];
    }
    if (q == 0) Eg[(chain * CC + c) * TT + ncol] = e1 + e2max;
}

// ---------------- combine helpers ----------------
__device__ __forceinline__ int wimax64(int v) {
#pragma unroll
    for (int m = 1; m < 64; m <<= 1) v = max(v, __shfl_xor(v, m, 64));
    return v;
}
__device__ __forceinline__ float wfmax64(float v) {
#pragma unroll
    for (int m = 1; m < 64; m <<= 1) v = fmaxf(v, __shfl_xor(v, m, 64));
    return v;
}
__device__ __forceinline__ float wfsum64(float v) {
#pragma unroll
    for (int m = 1; m < 64; m <<= 1) v += __shfl_xor(v, m, 64);
    return v;
}
__device__ __forceinline__ int fexp(float m) {
    unsigned u = (unsigned)__builtin_amdgcn_readfirstlane((int)__float_as_uint(m));
    return u ? (int)((u >> 23) & 255u) - 127 : 0;
}
__device__ __forceinline__ void loadrow(uint4 (&h)[8], const unsigned short* __restrict__ PgC,
                                        int c, int l) {
    const uint4* rp = (const uint4*)((const _Float16*)PgC + (size_t)c * 4096) + l * 8;
#pragma unroll
    for (int i = 0; i < 8; ++i) h[i] = rp[i];
}
__device__ __forceinline__ void mvstep(const uint4 (&hv)[8], int e, float* __restrict__ xws,
                                       int l, float& x, int& exX) {
    int emax = wimax64(e);
    float xt = ldexpf(x, e - emax);
    xws[l] = xt;  // wave-local slot; same-wave ds_write->ds_read ordered by lgkmcnt
    float acc = 0.f;
#pragma unroll
    for (int i = 0; i < 8; ++i) {
        union { uint4 u; _Float16 hh[8]; } pv;
        pv.u = hv[i];
        v4f xa = *(const v4f*)(xws + 8 * i);
        v4f xb = *(const v4f*)(xws + 8 * i + 4);
        acc = __builtin_fmaf((float)pv.hh[0], xa.x, acc);
        acc = __builtin_fmaf((float)pv.hh[1], xa.y, acc);
        acc = __builtin_fmaf((float)pv.hh[2], xa.z, acc);
        acc = __builtin_fmaf((float)pv.hh[3], xa.w, acc);
        acc = __builtin_fmaf((float)pv.hh[4], xb.x, acc);
        acc = __builtin_fmaf((float)pv.hh[5], xb.y, acc);
        acc = __builtin_fmaf((float)pv.hh[6], xb.z, acc);
        acc = __builtin_fmaf((float)pv.hh[7], xb.w, acc);
    }
    float am = wfmax64(acc);
    int e0 = fexp(am);
    x = ldexpf(acc, -e0);
    exX += e0 + emax;
}

// ---------------- combine: pipelined matvec chain + gold ----------------
__global__ __launch_bounds__(256, 1)
void crf_combine(const float* __restrict__ feats, const float* __restrict__ trans,
                 const int* __restrict__ mask, const int* __restrict__ tags,
                 const unsigned short* __restrict__ Pg, const int* __restrict__ Eg,
                 float* __restrict__ out) {
    __shared__ __align__(16) float xsh[4][TT];
    __shared__ float gred[4];

    const int chain = blockIdx.x;
    const int tid = threadIdx.x;
    const int w = tid >> 6, l = tid & 63;
    const unsigned short* PgC = Pg + (size_t)chain * CC * 4096;
    const int* EgC = Eg + chain * CC * TT;
    const float* fbase = feats + (size_t)chain * SS * TT;

    // chain length L (per-wave, redundant)
    int msum = 0;
#pragma unroll
    for (int k = 0; k < 8; ++k) msum += mask[chain * SS + 64 * k + l];
#pragma unroll
    for (int m = 1; m < 64; m <<= 1) msum += __shfl_xor(msum, m, 64);
    const int L = msum;

    // gold partial: 2 positions per thread
    float g = 0.f;
#pragma unroll
    for (int rep = 0; rep < 2; ++rep) {
        int t = tid + rep * 256;
        if (t < L) {
            int cur = tags[chain * SS + t];
            int prev = t ? tags[chain * SS + t - 1] : START_TAG;
            g += fbase[(size_t)t * TT + cur] + trans[prev * TT + cur];
        }
    }
    g = wfsum64(g);
    if (l == 0) gred[w] = g;

    // p0 (all waves redundantly; identical values)
    float pl = fbase[l] + trans[START_TAG * TT + l];
    float M0 = wfmax64(pl);
    float x = __builtin_amdgcn_exp2f((pl - M0) * LOG2E_F);
    int exX = 0;

    // pipelined matvec chain over CC chunk matrices
    uint4 hA[8], hB[8];
    int eA, eB;
    loadrow(hA, PgC, 0, l);
    eA = EgC[0 * TT + l];
#pragma unroll
    for (int c = 0; c < CC; c += 2) {
        loadrow(hB, PgC, c + 1, l);
        eB = EgC[(c + 1) * TT + l];
        mvstep(hA, eA, &xsh[w][0], l, x, exX);
        if (c + 2 < CC) {
            loadrow(hA, PgC, c + 2, l);
            eA = EgC[(c + 2) * TT + l];
        }
        mvstep(hB, eB, &xsh[w][0], l, x, exX);
    }

    // final contraction: fwd = log( sum_l x[l]*exp(trans[l][END]) ) + exX*ln2 + M0
    float val = x * expf(trans[l * TT + END_TAG]);
    val = wfsum64(val);
    float fwd = logf(val) + (float)exX * LN2_F + M0;

    __syncthreads();  // gred ready
    if (tid == 0) {
        float gold = gred[0] + gred[1] + gred[2] + gred[3] +
                     trans[tags[chain * SS + L - 1] * TT + END_TAG];
        atomicAdd(out, fwd - gold);
    }
}

extern "C" void kernel_launch(void* const* d_in, const int* in_sizes, int n_in,
                              void* d_out, int out_size, void* d_ws, size_t ws_size,
                              hipStream_t stream) {
    const float* feats = (const float*)d_in[0];
    const float* trans = (const float*)d_in[1];
    const int*   mask  = (const int*)d_in[2];
    const int*   tags  = (const int*)d_in[3];
    float* out = (float*)d_out;
    unsigned short* Pg = (unsigned short*)d_ws;
    int*       Eg = (int*)((char*)d_ws + WS_ECOL_OFF);

    crf_chunks<<<dim3(64 * CC), dim3(256), 0, stream>>>(feats, trans, mask, Pg, Eg, out);
    crf_combine<<<dim3(64), dim3(256), 0, stream>>>(feats, trans, mask, tags, Pg, Eg, out);
}